// Round 5
// baseline (859.358 us; speedup 1.0000x reference)
//
#include <hip/hip_runtime.h>
#include <hip/hip_bf16.h>

// Spiking attention, N=C=2048, T=10, heads=16, head_dim=128.
//
// Accuracy: spike decisions match an fp64 pipeline. Bulk GEMMs are bf16x2
// RNE-split MFMA (3 passes a1b1+a1b2+a2b1; sigma_dy ~ 3.5e-6). Closed-form IF
// epilogue certifies each channel (FLAG_EPS=4e-4 >= ~10 sigma of 10x-amplified
// dy) or flags it; flagged channels recomputed exactly in fp64 (rescue) ->
// masks bit-identical to fp64 pipeline regardless of MFMA shape/rounding.
// Constant input => IF spike train periodic, period J = first spike step;
// masks stored as J (u8); mask = LUT[J].
//
// R14 changes vs R13 (decision-invariant; operand bytes and per-element
// accumulation order bit-identical):
//  - GEMMs are now REGISTER-DIRECT (gemm_reg): no LDS, no barriers. The
//    fragment-major images make every MFMA operand a linear 1 KB wave
//    segment, so each wave global_load_dwordx4's fragments straight to
//    VGPRs. Per half-K-step: 8 loads + 12 MFMA, register double-buffered
//    one set ahead (counted vmcnt). Rationale: R13 showed the LDS path is
//    pipe+latency bound (LDS ~5.1k cy/round > MFMA 3.1k; DMA-drain barrier
//    locks all 4 waves for full mem latency; period 10.7k cy vs 3.1k MFMA
//    floor = 29% MfmaUtil). Register-direct removes both; TLP (12 waves/CU,
//    __launch_bounds__(256,3)) hides L2/L3 latency per-wave.
//
// ws layout (111.2 MB):
//   @0        MaskJ u8 25.17 MB   | after spike_attn: WOpk 16.78 MB
//   @25.17M   Bpk 50.33 MB        | after gemm<0>: WT f32 50.33
//                                 | after rescue: Xbpk 16.78
//   @75.50M   Apk 33.55 MB        | after gemm<0>: xbar f32 16.78
//   @109.05M  list u32 512K = 2 MB, then cnt u32

#define LIST_CAP (512u * 1024u)
#define FLAG_EPS 4e-4f

typedef __attribute__((ext_vector_type(8))) short short8;
typedef __attribute__((ext_vector_type(16))) float floatx16;

__device__ const unsigned d_LUT[16] = {0u, 0x3FFu, 0x2AAu, 0x124u, 0x88u,
                                       0x210u, 0x20u, 0x40u, 0x80u, 0x100u,
                                       0x200u, 0u, 0u, 0u, 0u, 0u};

// RNE split f32 -> two bf16 planes (raw u16 in low half).
__device__ __forceinline__ void bf16x2_rne(float a, unsigned& p1, unsigned& p2) {
  const unsigned u = __float_as_uint(a);
  const unsigned t1 = u + 0x7FFFu + ((u >> 16) & 1u);
  p1 = t1 >> 16;
  const float r = a - __uint_as_float(t1 & 0xFFFF0000u);
  const unsigned u2 = __float_as_uint(r);
  p2 = (u2 + 0x7FFFu + ((u2 >> 16) & 1u)) >> 16;
}

// Fragment-major within-image offset (shorts): image covers one plane of a
// 128-row x 32-k tile, 8 KB. chunk c (8 k-elems: ks=c>>1, kh=c&1), row r:
//   off = ((ks*4 + r>>5)*2 + kh)*256 + (r&31)*8
// => the 64-lane fragment for (ks, rowblock rb) is the linear 1 KB segment
//    at (ks*4 + rb)*512 shorts, lane l at +l*8.
__device__ __forceinline__ int frag_off(int c, int r) {
  return (((c >> 1) * 4 + (r >> 5)) * 2 + (c & 1)) * 256 + (r & 31) * 8;
}

__device__ __forceinline__ short8 gld(const unsigned short* p) {
  return *(const short8*)p;
}

// ---- wsplit: W columns -> packed fragment-major plane-tile images
// (image row = W column). Image (plane,ct,k0i) 8 KB, offset per frag_off.
template <int ZERO_CNT>
__global__ __launch_bounds__(256) void wsplit(
    const float* __restrict__ W0, const float* __restrict__ W1,
    const float* __restrict__ W2, unsigned short* __restrict__ Bpk,
    int NCT, unsigned* __restrict__ cnt) {
  if (ZERO_CNT && blockIdx.x == 0 && blockIdx.y == 0 && threadIdx.x == 0)
    *cnt = 0u;
  __shared__ float Wf[32 * 132];
  const int ct = blockIdx.x, k0 = blockIdx.y * 32;
  const int c0 = ct * 128;
  const int sel = c0 >> 11;
  const float* W = (sel == 0) ? W0 : ((sel == 1) ? W1 : W2);
  const int cc0 = c0 & 2047;
  const int t = threadIdx.x;

  const int kr = t >> 3, cq = (t & 7) * 16;
#pragma unroll
  for (int u = 0; u < 4; u++) {
    const float4 v = *(const float4*)(W + (size_t)(k0 + kr) * 2048 + cc0 + cq + 4 * u);
    *(float4*)&Wf[kr * 132 + cq + 4 * u] = v;
  }
  __syncthreads();

  const int cc = t >> 1, ch0 = (t & 1) * 2;
  unsigned short* img1 = Bpk + ((size_t)(0 * NCT + ct) * 64 + blockIdx.y) * 4096;
  unsigned short* img2 = Bpk + ((size_t)(1 * NCT + ct) * 64 + blockIdx.y) * 4096;
#pragma unroll
  for (int c = ch0; c < ch0 + 2; c++) {
    unsigned q1[8], q2[8];
#pragma unroll
    for (int e = 0; e < 8; e++) bf16x2_rne(Wf[(c * 8 + e) * 132 + cc], q1[e], q2[e]);
    const int off = frag_off(c, cc);
    uint4 P1, P2;
    P1.x = q1[0] | (q1[1] << 16); P1.y = q1[2] | (q1[3] << 16);
    P1.z = q1[4] | (q1[5] << 16); P1.w = q1[6] | (q1[7] << 16);
    P2.x = q2[0] | (q2[1] << 16); P2.y = q2[2] | (q2[3] << 16);
    P2.z = q2[4] | (q2[5] << 16); P2.w = q2[6] | (q2[7] << 16);
    *(uint4*)&img1[off] = P1;
    *(uint4*)&img2[off] = P2;
  }
}

// ---- asplit: row-major A (optionally relu(+-)) -> packed fragment-major
// images (image row = A row).
template <int RELU>
__global__ __launch_bounds__(256) void asplit(
    const float* __restrict__ src, unsigned short* __restrict__ Apk, int NRT) {
  const int rt = blockIdx.x, k0i = blockIdx.y;
  const int t = threadIdx.x;
  const int r = t >> 1, half = t & 1;
  int grow = rt * 128 + r;
  float sgn = 1.f;
  if (RELU && grow >= 2048) { grow -= 2048; sgn = -1.f; }
  const float* s = src + (size_t)grow * 2048 + k0i * 32 + half * 16;
  float f[16];
#pragma unroll
  for (int u = 0; u < 4; u++) {
    const float4 v = *(const float4*)(s + 4 * u);
    f[4 * u + 0] = v.x; f[4 * u + 1] = v.y;
    f[4 * u + 2] = v.z; f[4 * u + 3] = v.w;
  }
  if (RELU) {
#pragma unroll
    for (int e = 0; e < 16; e++) f[e] = fmaxf(sgn * f[e], 0.f);
  }
  unsigned q1[16], q2[16];
#pragma unroll
  for (int e = 0; e < 16; e++) bf16x2_rne(f[e], q1[e], q2[e]);

  unsigned short* img1 = Apk + ((size_t)(0 * NRT + rt) * 64 + k0i) * 4096;
  unsigned short* img2 = Apk + ((size_t)(1 * NRT + rt) * 64 + k0i) * 4096;
#pragma unroll
  for (int cc = 0; cc < 2; cc++) {
    const int c = half * 2 + cc;
    const int off = frag_off(c, r);
    const int e0 = cc * 8;
    uint4 P1, P2;
    P1.x = q1[e0 + 0] | (q1[e0 + 1] << 16); P1.y = q1[e0 + 2] | (q1[e0 + 3] << 16);
    P1.z = q1[e0 + 4] | (q1[e0 + 5] << 16); P1.w = q1[e0 + 6] | (q1[e0 + 7] << 16);
    P2.x = q2[e0 + 0] | (q2[e0 + 1] << 16); P2.y = q2[e0 + 2] | (q2[e0 + 3] << 16);
    P2.z = q2[e0 + 4] | (q2[e0 + 5] << 16); P2.w = q2[e0 + 6] | (q2[e0 + 7] << 16);
    *(uint4*)&img1[off] = P1;
    *(uint4*)&img2[off] = P2;
  }
}

// 12-MFMA cluster for one half-K set; per-element pass order a1b1->a1b2->a2b1.
__device__ __forceinline__ void mfma_set12(floatx16 (&acc)[2][2],
    const short8 (&A1)[2], const short8 (&A2)[2],
    const short8 (&B1)[2], const short8 (&B2)[2]) {
#pragma unroll
  for (int it = 0; it < 2; it++)
#pragma unroll
    for (int jt = 0; jt < 2; jt++)
      acc[it][jt] = __builtin_amdgcn_mfma_f32_32x32x16_bf16(A1[it], B1[jt], acc[it][jt], 0, 0, 0);
#pragma unroll
  for (int it = 0; it < 2; it++)
#pragma unroll
    for (int jt = 0; jt < 2; jt++)
      acc[it][jt] = __builtin_amdgcn_mfma_f32_32x32x16_bf16(A1[it], B2[jt], acc[it][jt], 0, 0, 0);
#pragma unroll
  for (int it = 0; it < 2; it++)
#pragma unroll
    for (int jt = 0; jt < 2; jt++)
      acc[it][jt] = __builtin_amdgcn_mfma_f32_32x32x16_bf16(A2[it], B1[jt], acc[it][jt], 0, 0, 0);
}

#define LOADSET(S, off)                                              \
  S##A1[0] = gld(bA1 + (off)); S##A1[1] = gld(bA1 + (off) + 512);    \
  S##A2[0] = gld(bA2 + (off)); S##A2[1] = gld(bA2 + (off) + 512);    \
  S##B1[0] = gld(bB1 + (off)); S##B1[1] = gld(bB1 + (off) + 512);    \
  S##B2[0] = gld(bB2 + (off)); S##B2[1] = gld(bB2 + (off) + 512);

// ---- gemm_reg: register-direct bf16x2 MFMA GEMM, 128x128 tile, 2x2 waves,
// 32x32x16 MFMA. No LDS, no barriers: each wave global-loads its fragments
// (linear 1 KB segments in the fragment-major images) straight to VGPRs.
// 128 half-K steps; per step: 8 global_load_dwordx4 + 12 MFMA; register
// double-buffered one step ahead (counted vmcnt inserted by compiler).
// Latency hidden by TLP: __launch_bounds__(256,3) -> 12 waves/CU.
// A/B frag layout (32x32x16): row = lane&31, k = (lane>>5)*8 + j.
// C/D layout (m74/m101): col = lane&31, row = (reg&3)+8*(reg>>2)+4*(lane>>5).
// MODE 0: closed-form IF -> MaskJ u8 + certify/flag. MODE 1: store y*0.1.
template <int MODE>
__global__ __launch_bounds__(256, 3) void gemm_reg(
    const unsigned short* __restrict__ Apk, const unsigned short* __restrict__ Bpk,
    int NRT, int NCT, unsigned char* __restrict__ MaskJ,
    unsigned* __restrict__ list, unsigned* __restrict__ cnt,
    float* __restrict__ Out) {
  const int tid = threadIdx.x;
  const int bx = blockIdx.x, by = blockIdx.y;
  const int lane = tid & 63, wave = tid >> 6;
  const int wr = wave >> 1, wc = wave & 1;
  const int lm = lane & 31, lg = lane >> 5;

  // per-wave fragment base pointers (lane-linear segments)
  const unsigned short* bA1 = Apk + ((size_t)(0 * NRT + by) * 64) * 4096 + 2 * wr * 512 + lane * 8;
  const unsigned short* bA2 = Apk + ((size_t)(1 * NRT + by) * 64) * 4096 + 2 * wr * 512 + lane * 8;
  const unsigned short* bB1 = Bpk + ((size_t)(0 * NCT + bx) * 64) * 4096 + 2 * wc * 512 + lane * 8;
  const unsigned short* bB2 = Bpk + ((size_t)(1 * NCT + bx) * 64) * 4096 + 2 * wc * 512 + lane * 8;

  floatx16 acc[2][2];
#pragma unroll
  for (int i = 0; i < 2; i++)
#pragma unroll
    for (int j = 0; j < 2; j++)
#pragma unroll
      for (int e = 0; e < 16; e++) acc[i][j][e] = 0.f;

  short8 PA1[2], PA2[2], PB1[2], PB2[2];  // even half-K set
  short8 QA1[2], QA2[2], QB1[2], QB2[2];  // odd half-K set

  // half-K step s: kt = s>>1, ks = s&1 -> image offset s*2048 shorts
  LOADSET(P, 0)
  for (int s = 0; s < 128; s += 2) {
    const size_t o1 = (size_t)(s + 1) * 2048;
    LOADSET(Q, o1)                       // prefetch set s+1
    mfma_set12(acc, PA1, PA2, PB1, PB2); // compute set s
    if (s + 2 < 128) {
      const size_t o2 = (size_t)(s + 2) * 2048;
      LOADSET(P, o2)                     // prefetch set s+2
    }
    mfma_set12(acc, QA1, QA2, QB1, QB2); // compute set s+1
  }

  // epilogue: C/D 32x32 layout
#pragma unroll
  for (int it = 0; it < 2; it++) {
#pragma unroll
    for (int jt = 0; jt < 2; jt++) {
      const int gn = bx * 128 + 64 * wc + 32 * jt + lm;
#pragma unroll
      for (int reg = 0; reg < 16; reg++) {
        const int gm = by * 128 + 64 * wr + 32 * it + (reg & 3) + 8 * (reg >> 2) + 4 * lg;
        const float y = acc[it][jt][reg];
        if (MODE == 1) {
          Out[(size_t)gm * 2048 + gn] = y * 0.1f;
        } else {
          float r = __builtin_amdgcn_rcpf(y);
          r = fminf(fmaxf(r, -1.0f), 12.0f);
          const float jf = floorf(r);
          const float d0 = fmaf(jf, y, -1.0f);
          const float i0 = fminf(fmaxf(jf, 1.0f), 10.0f);
          const float i1 = fminf(fmaxf(jf + 1.0f, 1.0f), 10.0f);
          const float e0 = fmaf(i0, y, -1.0f);
          const float e1 = fmaf(i1, y, -1.0f);
          const float mind = fminf(fabsf(e0), fabsf(e1));
          const unsigned J = (unsigned)(int)((d0 >= 0.0f) ? jf : jf + 1.0f);
          MaskJ[(size_t)gm * 6144 + gn] = (unsigned char)((J <= 10u) ? J : 0u);
          if (mind < FLAG_EPS) {
            const unsigned idx = atomicAdd(cnt, 1u);
            if (idx < LIST_CAP) list[idx] = ((unsigned)gm << 13) | (unsigned)gn;
          }
        }
      }
    }
  }
}

// ---- transpose W -> WT f32 (rescue source; runs after gemm<0>, aliases Bpk)
__global__ __launch_bounds__(256) void transpose_w(
    const float* __restrict__ W0, const float* __restrict__ W1,
    const float* __restrict__ W2, float* __restrict__ WT) {
  __shared__ float tile[32][33];
  const int k0 = blockIdx.x * 32;
  const int c0 = blockIdx.y * 32;
  const int sel = c0 >> 11;
  const float* W = (sel == 0) ? W0 : ((sel == 1) ? W1 : W2);
  const int cc0 = c0 & 2047;
  const int tx = threadIdx.x, ty = threadIdx.y;  // (32,8)
#pragma unroll
  for (int rep = 0; rep < 4; rep++)
    tile[ty + 8 * rep][tx] = W[(size_t)(k0 + ty + 8 * rep) * 2048 + cc0 + tx];
  __syncthreads();
#pragma unroll
  for (int rep = 0; rep < 4; rep++)
    WT[(size_t)(c0 + ty + 8 * rep) * 2048 + k0 + tx] = tile[tx][ty + 8 * rep];
}

// ---- rescue: fp64 dot for flagged channels -> first-spike J (u8)
__global__ __launch_bounds__(256) void rescue(
    const float* __restrict__ X, const float* __restrict__ WT,
    const unsigned* __restrict__ list, const unsigned* __restrict__ cnt,
    unsigned char* __restrict__ MaskJ) {
  const unsigned nItems = min(*cnt, LIST_CAP);
  const unsigned gtid = blockIdx.x * blockDim.x + threadIdx.x;
  const unsigned wave = gtid >> 6, lane = gtid & 63;
  const unsigned nWaves = (gridDim.x * blockDim.x) >> 6;

  for (unsigned i = wave; i < nItems; i += nWaves) {
    const unsigned e = list[i];
    const int r = (int)(e >> 13), c = (int)(e & 8191u);
    const float* xrow = X + (size_t)((r < 2048) ? r : r - 2048) * 2048;
    const float sg = (r < 2048) ? 1.f : -1.f;
    const float* wrow = WT + (size_t)c * 2048;
    double s = 0.0;
#pragma unroll
    for (int it = 0; it < 8; it++) {
      const int k = (it * 64 + (int)lane) * 4;
      const float4 xv = *(const float4*)(xrow + k);
      const float4 wv = *(const float4*)(wrow + k);
      const float a0 = fmaxf(sg * xv.x, 0.f);
      const float a1 = fmaxf(sg * xv.y, 0.f);
      const float a2 = fmaxf(sg * xv.z, 0.f);
      const float a3 = fmaxf(sg * xv.w, 0.f);
      s += (double)a0 * (double)wv.x + (double)a1 * (double)wv.y +
           (double)a2 * (double)wv.z + (double)a3 * (double)wv.w;
    }
#pragma unroll
    for (int off = 32; off > 0; off >>= 1) s += __shfl_down(s, off);
    if (lane == 0) {
      double v = 0.0;
      unsigned J = 0;
#pragma unroll
      for (int t = 0; t < 10; t++) {
        v += s;
        if (J == 0u && v >= 1.0) J = (unsigned)(t + 1);
      }
      MaskJ[(size_t)r * 6144 + c] = (unsigned char)J;
    }
  }
}

// ---- spike_attn: per-token attention. QK via wave-ballot bitpack + popcount
// (exact integers, bit-identical to the float dot); PV float with xv in
// conflict-free [m][d] LDS; output transpose (d,h)->d*16+h.
__global__ __launch_bounds__(256) void spike_attn(const unsigned char* __restrict__ MaskJ,
                                                  float* __restrict__ xbar) {
  const int n = blockIdx.x;
  const int tid = threadIdx.x;
  const int lane = tid & 63;

  __shared__ unsigned long long qpB[16][2], qnB[16][2], kpB[16][2], knB[16][2];
  __shared__ float xvT[16 * 132];   // [m][d], stride 132 (conflict-free)
  __shared__ float attnS[16 * 17];  // [h][m], stride 17 (conflict-free)
  __shared__ unsigned lutS[16];

  if (tid < 16) lutS[tid] = d_LUT[tid];
  __syncthreads();

  const unsigned char* mp = MaskJ + (size_t)n * 6144;
  const unsigned char* mn = MaskJ + (size_t)(n + 2048) * 6144;

  unsigned q_p[8], q_n[8], k_p[8], k_n[8], v_p[8], v_n[8];
#pragma unroll
  for (int j = 0; j < 8; j++) {
    const int c = tid + 256 * j;
    q_p[j] = lutS[mp[c]];        q_n[j] = lutS[mn[c]];
    k_p[j] = lutS[mp[2048 + c]]; k_n[j] = lutS[mn[2048 + c]];
    v_p[j] = lutS[mp[4096 + c]]; v_n[j] = lutS[mn[4096 + c]];
  }

  float acc[8];
#pragma unroll
  for (int j = 0; j < 8; j++) acc[j] = 0.f;

  for (int t = 0; t < 10; t++) {
    // ---- bitpack spikes (ballot) + xv floats
#pragma unroll
    for (int j = 0; j < 8; j++) {
      const int c = tid + 256 * j;  // wave-uniform upper bits
      const unsigned long long bqp = __ballot((q_p[j] >> t) & 1u);
      const unsigned long long bqn = __ballot((q_n[j] >> t) & 1u);
      const unsigned long long bkp = __ballot((k_p[j] >> t) & 1u);
      const unsigned long long bkn = __ballot((k_n[j] >> t) & 1u);
      const int h = c >> 7, word = (c >> 6) & 1;
      if (lane == 0) {
        qpB[h][word] = bqp; qnB[h][word] = bqn;
        kpB[h][word] = bkp; knB[h][word] = bkn;
      }
      const int m = h, d = c & 127;
      xvT[m * 132 + d] =
          (float)((v_p[j] >> t) & 1u) - (float)((v_n[j] >> t) & 1u);
    }
    __syncthreads();

    // ---- attn[h][m] = 0.125 * popcount dot (exact)
    {
      const int h = tid >> 4, m = tid & 15;
      int dot = 0;
#pragma unroll
      for (int w = 0; w < 2; w++) {
        const unsigned long long qp = qpB[h][w], qn = qnB[h][w];
        const unsigned long long kp = kpB[m][w], kn = knB[m][w];
        dot += __popcll(qp & kp) + __popcll(qn & kn) -
               __popcll(qp & kn) - __popcll(qn & kp);
      }
      attnS[h * 17 + m] = (float)dot * 0.125f;
    }
    __syncthreads();

    // ---- PV: output o = d*16 + h; h = tid&15 constant across j
    {
      const int h = tid & 15;
      float arow[16];
#pragma unroll
      for (int m = 0; m < 16; m++) arow[m] = attnS[h * 17 + m];
#pragma unroll
      for (int j = 0; j < 8; j++) {
        const int d = (tid + 256 * j) >> 4;
        float s = 0.f;
#pragma unroll
        for (int m = 0; m < 16; m++) s += arow[m] * xvT[m * 132 + d];
        acc[j] += s;
      }
    }
    __syncthreads();
  }

#pragma unroll
  for (int j = 0; j < 8; j++) xbar[(size_t)n * 2048 + tid + 256 * j] = acc[j];
}

extern "C" void kernel_launch(void* const* d_in, const int* in_sizes, int n_in,
                              void* d_out, int out_size, void* d_ws, size_t ws_size,
                              hipStream_t stream) {
  const float* x = (const float*)d_in[0];
  // d_in[1] = freqs_cis (unused)
  const float* wq = (const float*)d_in[2];
  const float* wk = (const float*)d_in[3];
  const float* wv = (const float*)d_in[4];
  const float* wo = (const float*)d_in[5];
  float* out = (float*)d_out;

  char* ws = (char*)d_ws;
  unsigned char* MaskJ = (unsigned char*)ws;                       // 25.17 MB @0
  unsigned short* WOpk = (unsigned short*)ws;                      // 16.78 MB (MaskJ dead)
  char* reg2 = ws + (size_t)4096 * 6144;                           // @25.17 MB
  unsigned short* Bpk = (unsigned short*)reg2;                     // 50.33 MB
  float* WT = (float*)reg2;                                        // (Bpk dead)
  unsigned short* Xbpk = (unsigned short*)reg2;                    // 16.78 MB (WT dead)
  char* reg3 = reg2 + (size_t)6144 * 2048 * 2 * 2;                 // @75.50 MB
  unsigned short* Apk = (unsigned short*)reg3;                     // 33.55 MB
  float* xbar = (float*)reg3;                                      // 16.78 MB (Apk dead)
  unsigned* list = (unsigned*)(reg3 + (size_t)4096 * 2048 * 2 * 2);  // 2 MB @109.05
  unsigned* cnt = list + LIST_CAP;

  wsplit<1><<<dim3(48, 64), 256, 0, stream>>>(wq, wk, wv, Bpk, 48, cnt);
  asplit<1><<<dim3(32, 64), 256, 0, stream>>>(x, Apk, 32);
  gemm_reg<0><<<dim3(48, 32), 256, 0, stream>>>(Apk, Bpk, 32, 48, MaskJ, list, cnt, nullptr);
  transpose_w<<<dim3(64, 192), dim3(32, 8), 0, stream>>>(wq, wk, wv, WT);
  rescue<<<2048, 256, 0, stream>>>(x, WT, list, cnt, MaskJ);
  spike_attn<<<2048, 256, 0, stream>>>(MaskJ, xbar);
  wsplit<0><<<dim3(16, 64), 256, 0, stream>>>(wo, wo, wo, WOpk, 16, nullptr);
  asplit<0><<<dim3(16, 64), 256, 0, stream>>>(xbar, Xbpk, 16);
  gemm_reg<1><<<dim3(16, 16), 256, 0, stream>>>(Xbpk, WOpk, 16, 16, nullptr, nullptr, nullptr, out);
}

// Round 7
// 770.327 us; speedup vs baseline: 1.1156x; 1.1156x over previous
//
#include <hip/hip_runtime.h>
#include <hip/hip_bf16.h>

// Spiking attention, N=C=2048, T=10, heads=16, head_dim=128.
//
// Accuracy: spike decisions match an fp64 pipeline. Bulk GEMMs are bf16x2
// RNE-split MFMA (3 passes a1b1+a1b2+a2b1; sigma_dy ~ 3.5e-6). Closed-form IF
// epilogue certifies each channel (FLAG_EPS=4e-4 >= ~10 sigma of 10x-amplified
// dy) or flags it; flagged channels recomputed exactly in fp64 (rescue) ->
// masks bit-identical to fp64 pipeline regardless of MFMA shape/rounding.
// Constant input => IF spike train periodic, period J = first spike step;
// masks stored as J (u8); mask = LUT[J].
//
// R16 changes vs R15 (bugfixes only; schedule unchanged):
//  - FIX 1 (crash candidate): drain s_waitcnt vmcnt(0) after the K-loop.
//    R15 ended the kernel with 8 LDS-DMA loads in flight; at s_endpgm the
//    workgroup's LDS can be reallocated while the DMA lands -> corruption
//    of other blocks / HSA abort.
//  - FIX 2 (correctness): gemm_ring<1> launched with NCH=128 (was 64).
//    Output GEMM has K=2048 = 64 K-tiles = 128 half-K chunks; NCH=64 both
//    halved the reduction and mis-derived the image stride (NCH>>1).
// Schedule (unchanged from R15): 3-slot LDS ring (48 KB -> 3 blocks/CU) at
// half-K (16 KB chunk) granularity, COUNTED vmcnt (never 0 in-loop):
//   vmcnt(4) [chunk c landed; c+1 in flight across barrier] -> s_barrier ->
//   issue4(c+2) into slot freed by c-1 -> 8 asm ds_read_b128 -> lgkmcnt(0)
//   + sched_barrier -> setprio(1); 12 MFMA; setprio(0).
// Chunk order (kt,ks) ascending, pass order a1b1->a1b2->a2b1 ->
// bit-identical output vs R9/R13.
//
// ws layout (111.2 MB):
//   @0        MaskJ u8 25.17 MB   | after spike_attn: WOpk 16.78 MB
//   @25.17M   Bpk 50.33 MB        | after gemm<0>: WT f32 50.33
//                                 | after rescue: Xbpk 16.78
//   @75.50M   Apk 33.55 MB        | after gemm<0>: xbar f32 16.78
//   @109.05M  list u32 512K = 2 MB, then cnt u32

#define LIST_CAP (512u * 1024u)
#define FLAG_EPS 4e-4f

typedef __attribute__((ext_vector_type(8))) short short8;
typedef __attribute__((ext_vector_type(16))) float floatx16;

__device__ const unsigned d_LUT[16] = {0u, 0x3FFu, 0x2AAu, 0x124u, 0x88u,
                                       0x210u, 0x20u, 0x40u, 0x80u, 0x100u,
                                       0x200u, 0u, 0u, 0u, 0u, 0u};

// RNE split f32 -> two bf16 planes (raw u16 in low half).
__device__ __forceinline__ void bf16x2_rne(float a, unsigned& p1, unsigned& p2) {
  const unsigned u = __float_as_uint(a);
  const unsigned t1 = u + 0x7FFFu + ((u >> 16) & 1u);
  p1 = t1 >> 16;
  const float r = a - __uint_as_float(t1 & 0xFFFF0000u);
  const unsigned u2 = __float_as_uint(r);
  p2 = (u2 + 0x7FFFu + ((u2 >> 16) & 1u)) >> 16;
}

// Fragment-major within-image offset (shorts): image covers one plane of a
// 128-row x 32-k tile, 8 KB, ks-major. chunk c (ks=c>>1, kh=c&1), row r:
//   off = ((ks*4 + r>>5)*2 + kh)*256 + (r&31)*8
__device__ __forceinline__ int frag_off(int c, int r) {
  return (((c >> 1) * 4 + (r >> 5)) * 2 + (c & 1)) * 256 + (r & 31) * 8;
}

// 32-bit LDS byte address for inline-asm DS ops.
__device__ __forceinline__ unsigned lds_addr32(const void* p) {
  return (unsigned)(size_t)(const __attribute__((address_space(3))) char*)p;
}

__device__ __forceinline__ short8 ds_read_b128a(unsigned addr) {
  short8 r;
  asm volatile("ds_read_b128 %0, %1" : "=v"(r) : "v"(addr));
  return r;
}

// ---- wsplit: W columns -> packed fragment-major plane-tile images
// (image row = W column). Image (plane,ct,k0i) 8 KB, offset per frag_off.
template <int ZERO_CNT>
__global__ __launch_bounds__(256) void wsplit(
    const float* __restrict__ W0, const float* __restrict__ W1,
    const float* __restrict__ W2, unsigned short* __restrict__ Bpk,
    int NCT, unsigned* __restrict__ cnt) {
  if (ZERO_CNT && blockIdx.x == 0 && blockIdx.y == 0 && threadIdx.x == 0)
    *cnt = 0u;
  __shared__ float Wf[32 * 132];
  const int ct = blockIdx.x, k0 = blockIdx.y * 32;
  const int c0 = ct * 128;
  const int sel = c0 >> 11;
  const float* W = (sel == 0) ? W0 : ((sel == 1) ? W1 : W2);
  const int cc0 = c0 & 2047;
  const int t = threadIdx.x;

  const int kr = t >> 3, cq = (t & 7) * 16;
#pragma unroll
  for (int u = 0; u < 4; u++) {
    const float4 v = *(const float4*)(W + (size_t)(k0 + kr) * 2048 + cc0 + cq + 4 * u);
    *(float4*)&Wf[kr * 132 + cq + 4 * u] = v;
  }
  __syncthreads();

  const int cc = t >> 1, ch0 = (t & 1) * 2;
  unsigned short* img1 = Bpk + ((size_t)(0 * NCT + ct) * 64 + blockIdx.y) * 4096;
  unsigned short* img2 = Bpk + ((size_t)(1 * NCT + ct) * 64 + blockIdx.y) * 4096;
#pragma unroll
  for (int c = ch0; c < ch0 + 2; c++) {
    unsigned q1[8], q2[8];
#pragma unroll
    for (int e = 0; e < 8; e++) bf16x2_rne(Wf[(c * 8 + e) * 132 + cc], q1[e], q2[e]);
    const int off = frag_off(c, cc);
    uint4 P1, P2;
    P1.x = q1[0] | (q1[1] << 16); P1.y = q1[2] | (q1[3] << 16);
    P1.z = q1[4] | (q1[5] << 16); P1.w = q1[6] | (q1[7] << 16);
    P2.x = q2[0] | (q2[1] << 16); P2.y = q2[2] | (q2[3] << 16);
    P2.z = q2[4] | (q2[5] << 16); P2.w = q2[6] | (q2[7] << 16);
    *(uint4*)&img1[off] = P1;
    *(uint4*)&img2[off] = P2;
  }
}

// ---- asplit: row-major A (optionally relu(+-)) -> packed fragment-major
// images (image row = A row).
template <int RELU>
__global__ __launch_bounds__(256) void asplit(
    const float* __restrict__ src, unsigned short* __restrict__ Apk, int NRT) {
  const int rt = blockIdx.x, k0i = blockIdx.y;
  const int t = threadIdx.x;
  const int r = t >> 1, half = t & 1;
  int grow = rt * 128 + r;
  float sgn = 1.f;
  if (RELU && grow >= 2048) { grow -= 2048; sgn = -1.f; }
  const float* s = src + (size_t)grow * 2048 + k0i * 32 + half * 16;
  float f[16];
#pragma unroll
  for (int u = 0; u < 4; u++) {
    const float4 v = *(const float4*)(s + 4 * u);
    f[4 * u + 0] = v.x; f[4 * u + 1] = v.y;
    f[4 * u + 2] = v.z; f[4 * u + 3] = v.w;
  }
  if (RELU) {
#pragma unroll
    for (int e = 0; e < 16; e++) f[e] = fmaxf(sgn * f[e], 0.f);
  }
  unsigned q1[16], q2[16];
#pragma unroll
  for (int e = 0; e < 16; e++) bf16x2_rne(f[e], q1[e], q2[e]);

  unsigned short* img1 = Apk + ((size_t)(0 * NRT + rt) * 64 + k0i) * 4096;
  unsigned short* img2 = Apk + ((size_t)(1 * NRT + rt) * 64 + k0i) * 4096;
#pragma unroll
  for (int cc = 0; cc < 2; cc++) {
    const int c = half * 2 + cc;
    const int off = frag_off(c, r);
    const int e0 = cc * 8;
    uint4 P1, P2;
    P1.x = q1[e0 + 0] | (q1[e0 + 1] << 16); P1.y = q1[e0 + 2] | (q1[e0 + 3] << 16);
    P1.z = q1[e0 + 4] | (q1[e0 + 5] << 16); P1.w = q1[e0 + 6] | (q1[e0 + 7] << 16);
    P2.x = q2[e0 + 0] | (q2[e0 + 1] << 16); P2.y = q2[e0 + 2] | (q2[e0 + 3] << 16);
    P2.z = q2[e0 + 4] | (q2[e0 + 5] << 16); P2.w = q2[e0 + 6] | (q2[e0 + 7] << 16);
    *(uint4*)&img1[off] = P1;
    *(uint4*)&img2[off] = P2;
  }
}

// ---- gemm_ring: bf16x2 MFMA GEMM, 128x128 tile, 2x2 waves, 32x32x16 MFMA.
// 3-slot LDS ring (48 KB -> 3 blocks/CU) at half-K (16 KB chunk) granularity
// with COUNTED vmcnt (never 0 in the loop). Section for chunk c:
//   vmcnt(4)            chunk c landed (issued 2 sections earlier);
//                       chunk c+1's 4 loads stay in flight across barrier
//   s_barrier           all waves' portions of c landed; readers of slot
//                       (c+2)%3 (chunk c-1) are done
//   issue4(c+2)         into freed slot
//   8x asm ds_read_b128 fragments of chunk c (linear 1 KB segments)
//   lgkmcnt(0); sched_barrier(0)   (rule 18)
//   setprio(1); 12 MFMA; setprio(0)
// Tail: dummy re-issues of the last chunk into dead slots keep the 4-issues/
// section invariant exact; final vmcnt(0) drain before the epilogue (no
// in-flight LDS-DMA at kernel exit). NCH = 2*Ktiles = 128 for both GEMMs.
// A/B frag layout (32x32x16): row = lane&31, k = (lane>>5)*8 + j.
// C/D layout (m74/m101): col = lane&31, row = (reg&3)+8*(reg>>2)+4*(lane>>5).
// MODE 0: closed-form IF -> MaskJ u8 + certify/flag. MODE 1: store y*0.1.
template <int MODE>
__global__ __launch_bounds__(256, 3) void gemm_ring(
    const unsigned short* __restrict__ Apk, const unsigned short* __restrict__ Bpk,
    int NRT, int NCT, int NCH, unsigned char* __restrict__ MaskJ,
    unsigned* __restrict__ list, unsigned* __restrict__ cnt,
    float* __restrict__ Out) {
  __shared__ unsigned short sh[3 * 8192];  // 48 KB: 3 slots x [4 planes x 4 KB]

  const int tid = threadIdx.x;
  const int bx = blockIdx.x, by = blockIdx.y;
  const int lane = tid & 63, wave = tid >> 6;
  const int wr = wave >> 1, wc = wave & 1;
  const int lm = lane & 31, lg = lane >> 5;

  // each wave stages its own plane: wave0=A p1, wave1=A p2, wave2=B p1, wave3=B p2
  const unsigned short* gbase =
      (wave < 2) ? (Apk + ((size_t)(wave * NRT + by) * (NCH >> 1)) * 4096)
                 : (Bpk + ((size_t)((wave - 2) * NCT + bx) * (NCH >> 1)) * 4096);

  auto issue4 = [&](int c, int slot) {
    const unsigned short* g = gbase + (size_t)c * 2048 + lane * 8;
#pragma unroll
    for (int i = 0; i < 4; i++)
      __builtin_amdgcn_global_load_lds(
          (const __attribute__((address_space(1))) unsigned*)(g + i * 512),
          (__attribute__((address_space(3))) unsigned*)(
              &sh[slot * 8192 + wave * 2048 + i * 512]),
          16, 0, 0);
  };

  floatx16 acc[2][2];
#pragma unroll
  for (int i = 0; i < 2; i++)
#pragma unroll
    for (int j = 0; j < 2; j++)
#pragma unroll
      for (int e = 0; e < 16; e++) acc[i][j][e] = 0.f;

  // fragment byte offsets within a slot (plane p at +p*4096 bytes)
  const unsigned aoff0 = (unsigned)((((2 * wr + 0) * 2 + lg) * 256 + lm * 8) * 2);
  const unsigned aoff1 = (unsigned)((((2 * wr + 1) * 2 + lg) * 256 + lm * 8) * 2);
  const unsigned boff0 = (unsigned)((((2 * wc + 0) * 2 + lg) * 256 + lm * 8) * 2);
  const unsigned boff1 = (unsigned)((((2 * wc + 1) * 2 + lg) * 256 + lm * 8) * 2);
  const unsigned shbase = lds_addr32(&sh[0]);

  // prologue: chunks 0,1 in flight
  issue4(0, 0);
  issue4(1, 1);

  int slot = 0;
  for (int c = 0; c < NCH; c++) {
    asm volatile("s_waitcnt vmcnt(4)" ::: "memory");  // chunk c landed; c+1 in flight
    __builtin_amdgcn_s_barrier();
    __builtin_amdgcn_sched_barrier(0);
    {
      const int cn = c + 2;
      int snxt = slot + 2; if (snxt >= 3) snxt -= 3;
      issue4((cn < NCH) ? cn : (NCH - 1), snxt);  // dummy at tail keeps count
    }
    const unsigned sb = shbase + (unsigned)(slot * 16384);
    short8 a1[2], a2[2], b1[2], b2[2];
    a1[0] = ds_read_b128a(sb + aoff0);
    a1[1] = ds_read_b128a(sb + aoff1);
    a2[0] = ds_read_b128a(sb + 4096u + aoff0);
    a2[1] = ds_read_b128a(sb + 4096u + aoff1);
    b1[0] = ds_read_b128a(sb + 8192u + boff0);
    b1[1] = ds_read_b128a(sb + 8192u + boff1);
    b2[0] = ds_read_b128a(sb + 12288u + boff0);
    b2[1] = ds_read_b128a(sb + 12288u + boff1);
    asm volatile("s_waitcnt lgkmcnt(0)" ::: "memory");
    __builtin_amdgcn_sched_barrier(0);
    __builtin_amdgcn_s_setprio(1);
#pragma unroll
    for (int it = 0; it < 2; it++)
#pragma unroll
      for (int jt = 0; jt < 2; jt++)
        acc[it][jt] = __builtin_amdgcn_mfma_f32_32x32x16_bf16(
            a1[it], b1[jt], acc[it][jt], 0, 0, 0);
#pragma unroll
    for (int it = 0; it < 2; it++)
#pragma unroll
      for (int jt = 0; jt < 2; jt++)
        acc[it][jt] = __builtin_amdgcn_mfma_f32_32x32x16_bf16(
            a1[it], b2[jt], acc[it][jt], 0, 0, 0);
#pragma unroll
    for (int it = 0; it < 2; it++)
#pragma unroll
      for (int jt = 0; jt < 2; jt++)
        acc[it][jt] = __builtin_amdgcn_mfma_f32_32x32x16_bf16(
            a2[it], b1[jt], acc[it][jt], 0, 0, 0);
    __builtin_amdgcn_s_setprio(0);
    slot = (slot == 2) ? 0 : slot + 1;
  }

  // drain: no in-flight LDS-DMA may survive the kernel (LDS is reallocated
  // at workgroup retirement -> corruption/fault). Once per block.
  asm volatile("s_waitcnt vmcnt(0)" ::: "memory");
  __builtin_amdgcn_sched_barrier(0);

  // epilogue: C/D 32x32 layout
#pragma unroll
  for (int it = 0; it < 2; it++) {
#pragma unroll
    for (int jt = 0; jt < 2; jt++) {
      const int gn = bx * 128 + 64 * wc + 32 * jt + lm;
#pragma unroll
      for (int reg = 0; reg < 16; reg++) {
        const int gm = by * 128 + 64 * wr + 32 * it + (reg & 3) + 8 * (reg >> 2) + 4 * lg;
        const float y = acc[it][jt][reg];
        if (MODE == 1) {
          Out[(size_t)gm * 2048 + gn] = y * 0.1f;
        } else {
          float r = __builtin_amdgcn_rcpf(y);
          r = fminf(fmaxf(r, -1.0f), 12.0f);
          const float jf = floorf(r);
          const float d0 = fmaf(jf, y, -1.0f);
          const float i0 = fminf(fmaxf(jf, 1.0f), 10.0f);
          const float i1 = fminf(fmaxf(jf + 1.0f, 1.0f), 10.0f);
          const float e0 = fmaf(i0, y, -1.0f);
          const float e1 = fmaf(i1, y, -1.0f);
          const float mind = fminf(fabsf(e0), fabsf(e1));
          const unsigned J = (unsigned)(int)((d0 >= 0.0f) ? jf : jf + 1.0f);
          MaskJ[(size_t)gm * 6144 + gn] = (unsigned char)((J <= 10u) ? J : 0u);
          if (mind < FLAG_EPS) {
            const unsigned idx = atomicAdd(cnt, 1u);
            if (idx < LIST_CAP) list[idx] = ((unsigned)gm << 13) | (unsigned)gn;
          }
        }
      }
    }
  }
}

// ---- transpose W -> WT f32 (rescue source; runs after gemm<0>, aliases Bpk)
__global__ __launch_bounds__(256) void transpose_w(
    const float* __restrict__ W0, const float* __restrict__ W1,
    const float* __restrict__ W2, float* __restrict__ WT) {
  __shared__ float tile[32][33];
  const int k0 = blockIdx.x * 32;
  const int c0 = blockIdx.y * 32;
  const int sel = c0 >> 11;
  const float* W = (sel == 0) ? W0 : ((sel == 1) ? W1 : W2);
  const int cc0 = c0 & 2047;
  const int tx = threadIdx.x, ty = threadIdx.y;  // (32,8)
#pragma unroll
  for (int rep = 0; rep < 4; rep++)
    tile[ty + 8 * rep][tx] = W[(size_t)(k0 + ty + 8 * rep) * 2048 + cc0 + tx];
  __syncthreads();
#pragma unroll
  for (int rep = 0; rep < 4; rep++)
    WT[(size_t)(c0 + ty + 8 * rep) * 2048 + k0 + tx] = tile[tx][ty + 8 * rep];
}

// ---- rescue: fp64 dot for flagged channels -> first-spike J (u8)
__global__ __launch_bounds__(256) void rescue(
    const float* __restrict__ X, const float* __restrict__ WT,
    const unsigned* __restrict__ list, const unsigned* __restrict__ cnt,
    unsigned char* __restrict__ MaskJ) {
  const unsigned nItems = min(*cnt, LIST_CAP);
  const unsigned gtid = blockIdx.x * blockDim.x + threadIdx.x;
  const unsigned wave = gtid >> 6, lane = gtid & 63;
  const unsigned nWaves = (gridDim.x * blockDim.x) >> 6;

  for (unsigned i = wave; i < nItems; i += nWaves) {
    const unsigned e = list[i];
    const int r = (int)(e >> 13), c = (int)(e & 8191u);
    const float* xrow = X + (size_t)((r < 2048) ? r : r - 2048) * 2048;
    const float sg = (r < 2048) ? 1.f : -1.f;
    const float* wrow = WT + (size_t)c * 2048;
    double s = 0.0;
#pragma unroll
    for (int it = 0; it < 8; it++) {
      const int k = (it * 64 + (int)lane) * 4;
      const float4 xv = *(const float4*)(xrow + k);
      const float4 wv = *(const float4*)(wrow + k);
      const float a0 = fmaxf(sg * xv.x, 0.f);
      const float a1 = fmaxf(sg * xv.y, 0.f);
      const float a2 = fmaxf(sg * xv.z, 0.f);
      const float a3 = fmaxf(sg * xv.w, 0.f);
      s += (double)a0 * (double)wv.x + (double)a1 * (double)wv.y +
           (double)a2 * (double)wv.z + (double)a3 * (double)wv.w;
    }
#pragma unroll
    for (int off = 32; off > 0; off >>= 1) s += __shfl_down(s, off);
    if (lane == 0) {
      double v = 0.0;
      unsigned J = 0;
#pragma unroll
      for (int t = 0; t < 10; t++) {
        v += s;
        if (J == 0u && v >= 1.0) J = (unsigned)(t + 1);
      }
      MaskJ[(size_t)r * 6144 + c] = (unsigned char)J;
    }
  }
}

// ---- spike_attn: per-token attention. QK via wave-ballot bitpack + popcount
// (exact integers, bit-identical to the float dot); PV float with xv in
// conflict-free [m][d] LDS; output transpose (d,h)->d*16+h.
__global__ __launch_bounds__(256) void spike_attn(const unsigned char* __restrict__ MaskJ,
                                                  float* __restrict__ xbar) {
  const int n = blockIdx.x;
  const int tid = threadIdx.x;
  const int lane = tid & 63;

  __shared__ unsigned long long qpB[16][2], qnB[16][2], kpB[16][2], knB[16][2];
  __shared__ float xvT[16 * 132];   // [m][d], stride 132 (conflict-free)
  __shared__ float attnS[16 * 17];  // [h][m], stride 17 (conflict-free)
  __shared__ unsigned lutS[16];

  if (tid < 16) lutS[tid] = d_LUT[tid];
  __syncthreads();

  const unsigned char* mp = MaskJ + (size_t)n * 6144;
  const unsigned char* mn = MaskJ + (size_t)(n + 2048) * 6144;

  unsigned q_p[8], q_n[8], k_p[8], k_n[8], v_p[8], v_n[8];
#pragma unroll
  for (int j = 0; j < 8; j++) {
    const int c = tid + 256 * j;
    q_p[j] = lutS[mp[c]];        q_n[j] = lutS[mn[c]];
    k_p[j] = lutS[mp[2048 + c]]; k_n[j] = lutS[mn[2048 + c]];
    v_p[j] = lutS[mp[4096 + c]]; v_n[j] = lutS[mn[4096 + c]];
  }

  float acc[8];
#pragma unroll
  for (int j = 0; j < 8; j++) acc[j] = 0.f;

  for (int t = 0; t < 10; t++) {
    // ---- bitpack spikes (ballot) + xv floats
#pragma unroll
    for (int j = 0; j < 8; j++) {
      const int c = tid + 256 * j;  // wave-uniform upper bits
      const unsigned long long bqp = __ballot((q_p[j] >> t) & 1u);
      const unsigned long long bqn = __ballot((q_n[j] >> t) & 1u);
      const unsigned long long bkp = __ballot((k_p[j] >> t) & 1u);
      const unsigned long long bkn = __ballot((k_n[j] >> t) & 1u);
      const int h = c >> 7, word = (c >> 6) & 1;
      if (lane == 0) {
        qpB[h][word] = bqp; qnB[h][word] = bqn;
        kpB[h][word] = bkp; knB[h][word] = bkn;
      }
      const int m = h, d = c & 127;
      xvT[m * 132 + d] =
          (float)((v_p[j] >> t) & 1u) - (float)((v_n[j] >> t) & 1u);
    }
    __syncthreads();

    // ---- attn[h][m] = 0.125 * popcount dot (exact)
    {
      const int h = tid >> 4, m = tid & 15;
      int dot = 0;
#pragma unroll
      for (int w = 0; w < 2; w++) {
        const unsigned long long qp = qpB[h][w], qn = qnB[h][w];
        const unsigned long long kp = kpB[m][w], kn = knB[m][w];
        dot += __popcll(qp & kp) + __popcll(qn & kn) -
               __popcll(qp & kn) - __popcll(qn & kp);
      }
      attnS[h * 17 + m] = (float)dot * 0.125f;
    }
    __syncthreads();

    // ---- PV: output o = d*16 + h; h = tid&15 constant across j
    {
      const int h = tid & 15;
      float arow[16];
#pragma unroll
      for (int m = 0; m < 16; m++) arow[m] = attnS[h * 17 + m];
#pragma unroll
      for (int j = 0; j < 8; j++) {
        const int d = (tid + 256 * j) >> 4;
        float s = 0.f;
#pragma unroll
        for (int m = 0; m < 16; m++) s += arow[m] * xvT[m * 132 + d];
        acc[j] += s;
      }
    }
    __syncthreads();
  }

#pragma unroll
  for (int j = 0; j < 8; j++) xbar[(size_t)n * 2048 + tid + 256 * j] = acc[j];
}

extern "C" void kernel_launch(void* const* d_in, const int* in_sizes, int n_in,
                              void* d_out, int out_size, void* d_ws, size_t ws_size,
                              hipStream_t stream) {
  const float* x = (const float*)d_in[0];
  // d_in[1] = freqs_cis (unused)
  const float* wq = (const float*)d_in[2];
  const float* wk = (const float*)d_in[3];
  const float* wv = (const float*)d_in[4];
  const float* wo = (const float*)d_in[5];
  float* out = (float*)d_out;

  char* ws = (char*)d_ws;
  unsigned char* MaskJ = (unsigned char*)ws;                       // 25.17 MB @0
  unsigned short* WOpk = (unsigned short*)ws;                      // 16.78 MB (MaskJ dead)
  char* reg2 = ws + (size_t)4096 * 6144;                           // @25.17 MB
  unsigned short* Bpk = (unsigned short*)reg2;                     // 50.33 MB
  float* WT = (float*)reg2;                                        // (Bpk dead)
  unsigned short* Xbpk = (unsigned short*)reg2;                    // 16.78 MB (WT dead)
  char* reg3 = reg2 + (size_t)6144 * 2048 * 2 * 2;                 // @75.50 MB
  unsigned short* Apk = (unsigned short*)reg3;                     // 33.55 MB
  float* xbar = (float*)reg3;                                      // 16.78 MB (Apk dead)
  unsigned* list = (unsigned*)(reg3 + (size_t)4096 * 2048 * 2 * 2);  // 2 MB @109.05
  unsigned* cnt = list + LIST_CAP;

  wsplit<1><<<dim3(48, 64), 256, 0, stream>>>(wq, wk, wv, Bpk, 48, cnt);
  asplit<1><<<dim3(32, 64), 256, 0, stream>>>(x, Apk, 32);
  gemm_ring<0><<<dim3(48, 32), 256, 0, stream>>>(Apk, Bpk, 32, 48, 128, MaskJ, list, cnt, nullptr);
  transpose_w<<<dim3(64, 192), dim3(32, 8), 0, stream>>>(wq, wk, wv, WT);
  rescue<<<2048, 256, 0, stream>>>(x, WT, list, cnt, MaskJ);
  spike_attn<<<2048, 256, 0, stream>>>(MaskJ, xbar);
  wsplit<0><<<dim3(16, 64), 256, 0, stream>>>(wo, wo, wo, WOpk, 16, nullptr);
  asplit<0><<<dim3(16, 64), 256, 0, stream>>>(xbar, Xbpk, 16);
  gemm_ring<1><<<dim3(16, 16), 256, 0, stream>>>(Xbpk, WOpk, 16, 16, 128, nullptr, nullptr, nullptr, out);
}